// Round 13
// baseline (473.228 us; speedup 1.0000x reference)
//
#include <hip/hip_runtime.h>
#include <hip/hip_bf16.h>
#include <cstddef>
#include <cstdint>

// ---------------- problem constants ----------------
constexpr int NN = 100000;   // nodes
constexpr int NE = 1600000;  // edges
constexpr int NF = 256;      // in features
constexpr int NH = 128;      // hidden
constexpr int NC = 32;       // classes

typedef __attribute__((ext_vector_type(8))) short short8v;   // 8 bf16 = 4 VGPR
typedef __attribute__((ext_vector_type(16))) float f32x16;   // MFMA 32x32 acc
typedef __attribute__((ext_vector_type(2))) float v2f;       // packed fp32 pair (v_pk_fma_f32)

// one-instruction packed RNE fp32->bf16x2 (no builtin on gfx950; T12/m240)
__device__ inline unsigned int cvtpk_bf16(float lo, float hi) {
    unsigned int r;
    asm("v_cvt_pk_bf16_f32 %0, %1, %2" : "=v"(r) : "v"(lo), "v"(hi));
    return r;
}

__device__ inline unsigned short f2bf(float a) {  // RNE fp32->bf16
    unsigned int ab = __float_as_uint(a);
    return (unsigned short)((ab + 0x7FFFu + ((ab >> 16) & 1u)) >> 16);
}

// 8 bf16 (uint4) scaled-accumulate into 4x v2f via packed FMA
__device__ inline void fma8pk(v2f* a, uint4 q, v2f v) {
    v2f p0, p1, p2, p3;
    p0.x = __uint_as_float(q.x << 16); p0.y = __uint_as_float(q.x & 0xFFFF0000u);
    p1.x = __uint_as_float(q.y << 16); p1.y = __uint_as_float(q.y & 0xFFFF0000u);
    p2.x = __uint_as_float(q.z << 16); p2.y = __uint_as_float(q.z & 0xFFFF0000u);
    p3.x = __uint_as_float(q.w << 16); p3.y = __uint_as_float(q.w & 0xFFFF0000u);
    a[0] = p0 * v + a[0];   // -> v_pk_fma_f32
    a[1] = p1 * v + a[1];
    a[2] = p2 * v + a[2];
    a[3] = p3 * v + a[3];
}

// ---------------- CSR build ----------------

__global__ __launch_bounds__(256) void zero_int_kernel(int* __restrict__ p, int n) {
    int i = blockIdx.x * 256 + threadIdx.x;
    if (i < n) p[i] = 0;
}

// hist also emits per-edge rank within its destination (atomic return -> store only).
__global__ __launch_bounds__(256) void hist_kernel(const int* __restrict__ edst,
                                                   int* __restrict__ counts,
                                                   int* __restrict__ rank, int ne) {
    int i = blockIdx.x * 256 + threadIdx.x;
    if (i < ne) rank[i] = atomicAdd(&counts[edst[i]], 1);
}

constexpr int SCAN_CHUNK = 1024;
constexpr int SCAN_NCH = (NN + SCAN_CHUNK - 1) / SCAN_CHUNK;  // 98

__global__ __launch_bounds__(256) void chunk_reduce_kernel(const int* __restrict__ counts,
                                                           int* __restrict__ chunkSums, int n) {
    __shared__ int sdata[256];
    int tid = threadIdx.x;
    int base = blockIdx.x * SCAN_CHUNK + tid * 4;
    int s = 0;
#pragma unroll
    for (int i = 0; i < 4; ++i)
        if (base + i < n) s += counts[base + i];
    sdata[tid] = s;
    __syncthreads();
    for (int off = 128; off > 0; off >>= 1) {
        if (tid < off) sdata[tid] += sdata[tid + off];
        __syncthreads();
    }
    if (tid == 0) chunkSums[blockIdx.x] = sdata[0];
}

__global__ void scan_chunks_kernel(const int* __restrict__ chunkSums,
                                   int* __restrict__ chunkOffs,
                                   int* __restrict__ rowptr, int nch, int n, int total) {
    if (blockIdx.x == 0 && threadIdx.x == 0) {
        int a = 0;
        for (int i = 0; i < nch; ++i) { int t = chunkSums[i]; chunkOffs[i] = a; a += t; }
        rowptr[n] = total;
    }
}

__global__ __launch_bounds__(256) void chunk_scan_kernel(const int* __restrict__ counts,
                                                         const int* __restrict__ chunkOffs,
                                                         int* __restrict__ rowptr, int n) {
    int tid = threadIdx.x;
    int b = blockIdx.x;
    int base = b * SCAN_CHUNK + tid * 4;
    int v[4];
    int s = 0;
#pragma unroll
    for (int i = 0; i < 4; ++i) {
        v[i] = (base + i < n) ? counts[base + i] : 0;
        s += v[i];
    }
    int lane = tid & 63, wid = tid >> 6;
    int x = s;
#pragma unroll
    for (int d = 1; d < 64; d <<= 1) {
        int y = __shfl_up(x, d);
        if (lane >= d) x += y;
    }
    __shared__ int wtot[4];
    if (lane == 63) wtot[wid] = x;
    __syncthreads();
    int woff = 0;
    for (int w = 0; w < wid; ++w) woff += wtot[w];
    int excl = chunkOffs[b] + woff + (x - s);
#pragma unroll
    for (int i = 0; i < 4; ++i) {
        if (base + i < n) rowptr[base + i] = excl;
        excl += v[i];
    }
}

// XCD-pinned, atomic-free scatter (proven R7: WRITE_SIZE merge works).
constexpr int SL_EDGES = 4096;
constexpr int NSLICES = (NE + SL_EDGES - 1) / SL_EDGES;  // 391
constexpr int DPX = NN / 8;                              // 12500 dsts per XCD range

__global__ __launch_bounds__(256) void scatter_kernel(const int* __restrict__ esrc,
                                                      const int* __restrict__ edst,
                                                      const float* __restrict__ eval_,
                                                      const int* __restrict__ rowptr,
                                                      const int* __restrict__ rank,
                                                      int2* __restrict__ pedge, int ne) {
    const int xcd = blockIdx.x & 7;
    const int slice = blockIdx.x >> 3;
    const int lo = xcd * DPX;
    const int hi = lo + DPX;
    const int base = slice * SL_EDGES;
#pragma unroll
    for (int k = 0; k < SL_EDGES; k += 256) {
        int i = base + k + threadIdx.x;
        if (i < ne) {
            int d = edst[i];
            if (d >= lo && d < hi) {
                int pos = rowptr[d] + rank[i];
                pedge[pos] = make_int2(esrc[i], __float_as_int(eval_[i]));
            }
        }
    }
}

// ---------------- weight transpose + bf16 round (single bf16 weights; lo terms
// dropped: error ~ sqrt(K)*|a||b|*2^-9 ≈ 2e-3 on support, ~1e-2 on out) ----------------
__global__ __launch_bounds__(256) void wconv_kernel(const float* __restrict__ W1,
                                                    const float* __restrict__ W2,
                                                    unsigned short* __restrict__ w1h,
                                                    unsigned short* __restrict__ w2h) {
    int i = blockIdx.x * 256 + threadIdx.x;
    if (i < NF * NH) {
        int k = i / NH, n = i % NH;
        w1h[n * NF + k] = f2bf(W1[i]);
    } else if (i < NF * NH + NH * NC) {
        int j = i - NF * NH;
        int k = j / NC, n = j % NC;
        w2h[n * NH + k] = f2bf(W2[j]);
    }
}

// ---------------- gemm1: C_bf16[M,BN] = A_f32[M,K] @ B[K,BN] ----------------
// A split hi/lo (a ≈ ah+al to 2^-17); B single bf16. 2 MFMA per tile.
// BK=32 (2 MFMA k-groups per stage) -> half the barriers of BK=16.
template <int WM, int WN, int RT, int CT, int K>
__global__ __launch_bounds__(WM * WN * 64) void gemm_mfma_kernel(
    const float* __restrict__ A,
    const unsigned short* __restrict__ Bth,
    unsigned short* __restrict__ C, int M) {
    constexpr int NTHREADS = WM * WN * 64;
    constexpr int BM = WM * RT * 32;
    constexpr int BN = WN * CT * 32;
    constexpr int ATILES = WM * RT;
    constexpr int BTILES = WN * CT;
    constexpr int A_KS = ATILES * 1024;       // one k-group of A frags
    constexpr int A_LO = 2 * A_KS;            // A_HI at 0 (2 ks), A_LO after
    constexpr int B_HI = 4 * A_KS;
    constexpr int B_KS = BTILES * 1024;
    __shared__ __align__(16) unsigned char smem[B_HI + 2 * B_KS];

    const int tid = threadIdx.x;
    const int lane = tid & 63;
    const int w = tid >> 6;
    const int wm = w % WM;
    const int wn = w / WM;
    const int m0 = blockIdx.x * BM;

    f32x16 acc[RT][CT];
#pragma unroll
    for (int r = 0; r < RT; ++r)
#pragma unroll
        for (int c = 0; c < CT; ++c) acc[r][c] = (f32x16)(0.0f);

    for (int k0 = 0; k0 < K; k0 += 32) {
        // ---- stage A: BM x 32 fp32 -> bf16 hi/lo, fragment-ordered ----
#pragma unroll
        for (int idx = tid; idx < BM * 8; idx += NTHREADS) {
            int row = idx >> 3, kq = idx & 7;       // kq: float4 within 32-k
            int ks = kq >> 2, kq2 = kq & 3;
            int grow = m0 + row;
            float4 v = make_float4(0.f, 0.f, 0.f, 0.f);
            if (grow < M) v = *reinterpret_cast<const float4*>(&A[(size_t)grow * K + k0 + kq * 4]);
            uint2 hh, ll;
            hh.x = cvtpk_bf16(v.x, v.y);
            hh.y = cvtpk_bf16(v.z, v.w);
            float h0 = __uint_as_float(hh.x << 16);
            float h1 = __uint_as_float(hh.x & 0xFFFF0000u);
            float h2 = __uint_as_float(hh.y << 16);
            float h3 = __uint_as_float(hh.y & 0xFFFF0000u);
            ll.x = cvtpk_bf16(v.x - h0, v.y - h1);
            ll.y = cvtpk_bf16(v.z - h2, v.w - h3);
            int off = ks * A_KS + (row >> 5) * 1024 + (kq2 >> 1) * 512 + (row & 31) * 16 + (kq2 & 1) * 8;
            *reinterpret_cast<uint2*>(&smem[off]) = hh;
            *reinterpret_cast<uint2*>(&smem[A_LO + off]) = ll;
        }
        // ---- stage B: BN x 32 bf16, fragment-ordered ----
#pragma unroll
        for (int idx = tid; idx < BN * 4; idx += NTHREADS) {
            int n = idx >> 2, kgg = idx & 3;
            int ks = kgg >> 1, kg = kgg & 1;
            uint4 vh = *reinterpret_cast<const uint4*>(&Bth[(size_t)n * K + k0 + kgg * 8]);
            int off = B_HI + ks * B_KS + (n >> 5) * 1024 + kg * 512 + (n & 31) * 16;
            *reinterpret_cast<uint4*>(&smem[off]) = vh;
        }
        __syncthreads();

#pragma unroll
        for (int ks = 0; ks < 2; ++ks) {
            short8v ah[RT], al[RT], bh[CT];
#pragma unroll
            for (int r = 0; r < RT; ++r) {
                int off = ks * A_KS + (wm * RT + r) * 1024 + lane * 16;
                ah[r] = *reinterpret_cast<const short8v*>(&smem[off]);
                al[r] = *reinterpret_cast<const short8v*>(&smem[A_LO + off]);
            }
#pragma unroll
            for (int c = 0; c < CT; ++c) {
                int off = B_HI + ks * B_KS + (wn * CT + c) * 1024 + lane * 16;
                bh[c] = *reinterpret_cast<const short8v*>(&smem[off]);
            }
#pragma unroll
            for (int r = 0; r < RT; ++r)
#pragma unroll
                for (int c = 0; c < CT; ++c) {
                    acc[r][c] = __builtin_amdgcn_mfma_f32_32x32x16_bf16(ah[r], bh[c], acc[r][c], 0, 0, 0);
                    acc[r][c] = __builtin_amdgcn_mfma_f32_32x32x16_bf16(al[r], bh[c], acc[r][c], 0, 0, 0);
                }
        }
        __syncthreads();
    }

    // ---- epilogue: C[row][col], col=lane&31, row=(reg&3)+8*(reg>>2)+4*(lane>>5) ----
    const int lo32 = lane & 31;
    const int hi32 = lane >> 5;
#pragma unroll
    for (int r = 0; r < RT; ++r)
#pragma unroll
        for (int c = 0; c < CT; ++c) {
            int rowbase = m0 + (wm * RT + r) * 32 + 4 * hi32;
            int col = (wn * CT + c) * 32 + lo32;
#pragma unroll
            for (int g = 0; g < 4; ++g)
#pragma unroll
                for (int q = 0; q < 4; ++q) {
                    int row = rowbase + 8 * g + q;
                    if (row < M) C[(size_t)row * BN + col] = f2bf(acc[r][c][g * 4 + q]);
                }
        }
}

// ---------------- gemm2: C_bf16[M,32] = A_bf16[M,128] @ W2_bf16 (1 MFMA/acc) ----------------
__global__ __launch_bounds__(128) void gemm2_mfma_kernel(const unsigned short* __restrict__ A,
                                                         const unsigned short* __restrict__ Bth,
                                                         unsigned short* __restrict__ C, int M) {
    constexpr int BM = 128, BN = 32, K = NH;
    constexpr int B_HI = 4096;
    __shared__ __align__(16) unsigned char smem[5120];

    const int tid = threadIdx.x;
    const int lane = tid & 63;
    const int wm = tid >> 6;  // 2 waves: m-split
    const int m0 = blockIdx.x * BM;

    f32x16 acc[2];
    acc[0] = (f32x16)(0.0f);
    acc[1] = (f32x16)(0.0f);

    for (int k0 = 0; k0 < K; k0 += 16) {
#pragma unroll
        for (int i = 0; i < 2; ++i) {
            int idx = tid + i * 128;
            int row = idx >> 1, kg = idx & 1;
            int gr = m0 + row;
            uint4 v = make_uint4(0, 0, 0, 0);
            if (gr < M) v = *reinterpret_cast<const uint4*>(&A[(size_t)gr * K + k0 + kg * 8]);
            int off = (row >> 5) * 1024 + kg * 512 + (row & 31) * 16;
            *reinterpret_cast<uint4*>(&smem[off]) = v;
        }
        if (tid < 64) {
            int n = tid >> 1, kg = tid & 1;
            uint4 vh = *reinterpret_cast<const uint4*>(&Bth[(size_t)n * K + k0 + kg * 8]);
            *reinterpret_cast<uint4*>(&smem[B_HI + kg * 512 + n * 16]) = vh;
        }
        __syncthreads();

        short8v a0 = *reinterpret_cast<const short8v*>(&smem[(wm * 2 + 0) * 1024 + lane * 16]);
        short8v a1 = *reinterpret_cast<const short8v*>(&smem[(wm * 2 + 1) * 1024 + lane * 16]);
        short8v bh = *reinterpret_cast<const short8v*>(&smem[B_HI + lane * 16]);
        acc[0] = __builtin_amdgcn_mfma_f32_32x32x16_bf16(a0, bh, acc[0], 0, 0, 0);
        acc[1] = __builtin_amdgcn_mfma_f32_32x32x16_bf16(a1, bh, acc[1], 0, 0, 0);
        __syncthreads();
    }

    const int lo32 = lane & 31;
    const int hi32 = lane >> 5;
#pragma unroll
    for (int r = 0; r < 2; ++r) {
        int rowbase = m0 + (wm * 2 + r) * 32 + 4 * hi32;
#pragma unroll
        for (int g = 0; g < 4; ++g)
#pragma unroll
            for (int q = 0; q < 4; ++q) {
                int row = rowbase + 8 * g + q;
                if (row < M) C[(size_t)row * BN + lo32] = f2bf(acc[r][g * 4 + q]);
            }
    }
}

// ---------------- aggregation (SpMM via CSR, bf16 activations, packed fp32 math) ----------------

// One WAVE per node (node = nbase + blockIdx*4 + wid; split launches for profile
// visibility). 256B bf16 row = 16 lanes x uint4; 4 edge streams x 4-deep unroll.
__global__ __launch_bounds__(256) void agg_nh_kernel(const unsigned short* __restrict__ support,
                                                     const int* __restrict__ rowptr,
                                                     const int2* __restrict__ pedge,
                                                     const float* __restrict__ bias,
                                                     unsigned short* __restrict__ outh,
                                                     int nbase) {
    const int wid = threadIdx.x >> 6;
    const int lane = threadIdx.x & 63;
    const int g = lane >> 4;      // 4 edge streams
    const int f = lane & 15;      // 16B chunk within the 256B row
    const int node = nbase + blockIdx.x * 4 + wid;
    const int beg = rowptr[node];
    const int end = rowptr[node + 1];

    v2f a0[4] = {}, a1[4] = {}, a2[4] = {}, a3[4] = {};

    int e = beg + g;
    for (; e + 12 < end; e += 16) {   // this stream: edges e, e+4, e+8, e+12
        int2 e0 = pedge[e];
        int2 e1 = pedge[e + 4];
        int2 e2 = pedge[e + 8];
        int2 e3 = pedge[e + 12];
        uint4 q0 = reinterpret_cast<const uint4*>(&support[(size_t)e0.x * NH])[f];
        uint4 q1 = reinterpret_cast<const uint4*>(&support[(size_t)e1.x * NH])[f];
        uint4 q2 = reinterpret_cast<const uint4*>(&support[(size_t)e2.x * NH])[f];
        uint4 q3 = reinterpret_cast<const uint4*>(&support[(size_t)e3.x * NH])[f];
        float v0 = __int_as_float(e0.y), v1 = __int_as_float(e1.y);
        float v2 = __int_as_float(e2.y), v3 = __int_as_float(e3.y);
        fma8pk(a0, q0, (v2f){v0, v0});
        fma8pk(a1, q1, (v2f){v1, v1});
        fma8pk(a2, q2, (v2f){v2, v2});
        fma8pk(a3, q3, (v2f){v3, v3});
    }
    for (; e + 4 < end; e += 8) {     // mid-tier: 2 edges in flight
        int2 e0 = pedge[e];
        int2 e1 = pedge[e + 4];
        uint4 q0 = reinterpret_cast<const uint4*>(&support[(size_t)e0.x * NH])[f];
        uint4 q1 = reinterpret_cast<const uint4*>(&support[(size_t)e1.x * NH])[f];
        float v0 = __int_as_float(e0.y), v1 = __int_as_float(e1.y);
        fma8pk(a0, q0, (v2f){v0, v0});
        fma8pk(a1, q1, (v2f){v1, v1});
    }
    for (; e < end; e += 4) {
        int2 ed = pedge[e];
        uint4 q = reinterpret_cast<const uint4*>(&support[(size_t)ed.x * NH])[f];
        float v = __int_as_float(ed.y);
        fma8pk(a0, q, (v2f){v, v});
    }

    float r[8];
#pragma unroll
    for (int j = 0; j < 4; ++j) {
        v2f s = a0[j] + a1[j] + a2[j] + a3[j];   // v_pk_add_f32
        float sx = s.x, sy = s.y;
        sx += __shfl_xor(sx, 16);
        sx += __shfl_xor(sx, 32);
        sy += __shfl_xor(sy, 16);
        sy += __shfl_xor(sy, 32);
        r[2 * j] = sx;
        r[2 * j + 1] = sy;
    }

    if (g == 0) {
        float4 b0 = reinterpret_cast<const float4*>(bias)[2 * f];
        float4 b1 = reinterpret_cast<const float4*>(bias)[2 * f + 1];
        float r0 = fmaxf(r[0] + b0.x, 0.f), r1 = fmaxf(r[1] + b0.y, 0.f);
        float r2 = fmaxf(r[2] + b0.z, 0.f), r3 = fmaxf(r[3] + b0.w, 0.f);
        float r4 = fmaxf(r[4] + b1.x, 0.f), r5 = fmaxf(r[5] + b1.y, 0.f);
        float r6 = fmaxf(r[6] + b1.z, 0.f), r7 = fmaxf(r[7] + b1.w, 0.f);
        uint4 o;
        o.x = cvtpk_bf16(r0, r1);
        o.y = cvtpk_bf16(r2, r3);
        o.z = cvtpk_bf16(r4, r5);
        o.w = cvtpk_bf16(r6, r7);
        reinterpret_cast<uint4*>(&outh[(size_t)node * NH])[f] = o;
    }
}

// One WAVE per node. 64B bf16 row = 4 lanes x uint4; 16 edge streams in flight.
__global__ __launch_bounds__(256) void agg_nc_kernel(const unsigned short* __restrict__ support,
                                                     const int* __restrict__ rowptr,
                                                     const int2* __restrict__ pedge,
                                                     const float* __restrict__ bias,
                                                     float* __restrict__ out) {
    const int wid = threadIdx.x >> 6;
    const int lane = threadIdx.x & 63;
    const int g = lane >> 2;      // 16 edge streams
    const int f = lane & 3;       // 16B chunk within the 64B row
    const int node = blockIdx.x * 4 + wid;
    const int beg = rowptr[node];
    const int end = rowptr[node + 1];

    v2f a[4] = {};
    for (int e = beg + g; e < end; e += 16) {
        int2 ed = pedge[e];
        uint4 q = reinterpret_cast<const uint4*>(&support[(size_t)ed.x * NC])[f];
        float v = __int_as_float(ed.y);
        fma8pk(a, q, (v2f){v, v});
    }
    float r[8];
#pragma unroll
    for (int j = 0; j < 4; ++j) {
        float sx = a[j].x, sy = a[j].y;
        sx += __shfl_xor(sx, 4);
        sx += __shfl_xor(sx, 8);
        sx += __shfl_xor(sx, 16);
        sx += __shfl_xor(sx, 32);
        sy += __shfl_xor(sy, 4);
        sy += __shfl_xor(sy, 8);
        sy += __shfl_xor(sy, 16);
        sy += __shfl_xor(sy, 32);
        r[2 * j] = sx;
        r[2 * j + 1] = sy;
    }
    if (g == 0) {
        float4 b0 = reinterpret_cast<const float4*>(bias)[2 * f];
        float4 b1 = reinterpret_cast<const float4*>(bias)[2 * f + 1];
        float4 w0 = make_float4(r[0] + b0.x, r[1] + b0.y, r[2] + b0.z, r[3] + b0.w);
        float4 w1 = make_float4(r[4] + b1.x, r[5] + b1.y, r[6] + b1.z, r[7] + b1.w);
        reinterpret_cast<float4*>(&out[(size_t)node * NC])[2 * f] = w0;
        reinterpret_cast<float4*>(&out[(size_t)node * NC])[2 * f + 1] = w1;
    }
}

// ---------------- launch ----------------

extern "C" void kernel_launch(void* const* d_in, const int* in_sizes, int n_in,
                              void* d_out, int out_size, void* d_ws, size_t ws_size,
                              hipStream_t stream) {
    const float* x = (const float*)d_in[0];
    const int* esrc = (const int*)d_in[1];
    const int* edst = (const int*)d_in[2];
    const float* eval_ = (const float*)d_in[3];
    const float* W1 = (const float*)d_in[4];
    const float* b1 = (const float*)d_in[5];
    const float* W2 = (const float*)d_in[6];
    const float* b2 = (const float*)d_in[7];
    float* out = (float*)d_out;

    // workspace layout (all 16B-aligned)
    char* ws = (char*)d_ws;
    unsigned short* sup = (unsigned short*)(ws + 0);    // 25,600,000 B bf16 support1 / support2
    int* rank = (int*)(ws + 0);                         // 6,400,000 B — ALIASES sup:
                                                        //   written by hist, read by scatter,
                                                        //   dead before gemm1 writes sup
    unsigned short* hbuf = (unsigned short*)(ws + 25600000);  // 25,600,000 B bf16 h
    int* rowptr = (int*)(ws + 51200000);                // 400,128 B
    int* counts = (int*)(ws + 51600128);                // 400,384 B
    int2* pedge = (int2*)(ws + 52000512);               // 12,800,000 B
    int* chunkSums = (int*)(ws + 64800512);             // 512 B
    int* chunkOffs = (int*)(ws + 64801024);             // 512 B
    unsigned short* w1h = (unsigned short*)(ws + 64801536);  // 65,536 B
    unsigned short* w2h = (unsigned short*)(ws + 64867072);  // 8,192 B
    (void)ws_size; (void)in_sizes; (void)n_in; (void)out_size;

    // ---- weight conversion (independent of CSR build) ----
    wconv_kernel<<<(NF * NH + NH * NC + 255) / 256, 256, 0, stream>>>(W1, W2, w1h, w2h);

    // ---- CSR build: hist(+rank) -> scan -> XCD-pinned atomic-free scatter ----
    zero_int_kernel<<<(NN + 255) / 256, 256, 0, stream>>>(counts, NN);
    hist_kernel<<<(NE + 255) / 256, 256, 0, stream>>>(edst, counts, rank, NE);
    chunk_reduce_kernel<<<SCAN_NCH, 256, 0, stream>>>(counts, chunkSums, NN);
    scan_chunks_kernel<<<1, 64, 0, stream>>>(chunkSums, chunkOffs, rowptr, SCAN_NCH, NN, NE);
    chunk_scan_kernel<<<SCAN_NCH, 256, 0, stream>>>(counts, chunkOffs, rowptr, NN);
    scatter_kernel<<<NSLICES * 8, 256, 0, stream>>>(esrc, edst, eval_, rowptr, rank, pedge, NE);

    // ---- layer 1: sup = bf16(x @ W1); h = bf16(relu(Agg(sup) + b1)) ----
    gemm_mfma_kernel<2, 2, 2, 2, NF><<<(NN + 127) / 128, 256, 0, stream>>>(x, w1h, sup, NN);
    // split into two dispatches for rocprof top-k visibility (~38us each)
    agg_nh_kernel<<<NN / 8, 256, 0, stream>>>(sup, rowptr, pedge, b1, hbuf, 0);
    agg_nh_kernel<<<NN / 8, 256, 0, stream>>>(sup, rowptr, pedge, b1, hbuf, NN / 2);

    // ---- layer 2: sup = bf16(h @ W2); out = Agg(sup) + b2 (fp32) ----
    gemm2_mfma_kernel<<<(NN + 127) / 128, 128, 0, stream>>>(hbuf, w2h, sup, NN);
    agg_nc_kernel<<<NN / 4, 256, 0, stream>>>(sup, rowptr, pedge, b2, out);
}